// Round 5
// baseline (277.590 us; speedup 1.0000x reference)
//
#include <hip/hip_runtime.h>

// 2-layer tanh RNN, T=2048, B=2048, EMB=10, HID=8, NCLS=4, VOCAB=4.
// Time-chunking with 256-step warm-up (contraction rho^256 ~ 4e-3).
//
// R8 changes (from R7 post-mortem: distance-2 pipeline + trees ADDED issue
// work (busy 822->1028 cy/step) and stalls barely moved -> the idle is not
// memory waits. R3-R7 invariant: wall/step ~ per-SIMD aggregate issue +
// single-wave stall tax. Need a 2nd resident wave carrying NEW work):
//  PRODUCER/CONSUMER LAYER SPLIT, 128-thread blocks, 64 chains/block:
//   wave0: L0 recurrence + low half of Wih1@h0  (48 pk_fma/step)
//   wave1: high half Wih1@h0 + Whh1@h1 + tanh + FC + store (48 pk_fma/step)
//  Handoff: (h0, z_lo) via 2-slot LDS ring, 6 ds_write_b64 / 6 ds_read_b64.
//  Sync: raw s_barrier + lgkmcnt(0) per step; vmcnt NOT drained (x loads and
//  stores stay in flight across barriers). Zero redundant work; balanced
//  48/48 split; the two async waves/SIMD fill each other's stalls.

#define T_LEN 2048
#define B_LEN 2048
#define EMB_D 10
#define NCHUNK 32
#define CHUNK (T_LEN / NCHUNK)   // 64
#define WARM 256
#define KSCALE 2.8853900817779268f   // 2*log2(e)

typedef float v2f __attribute__((ext_vector_type(2)));

#define PINV(v) asm volatile("" : "+v"(v))
#define PINS(v) asm volatile("" : "+s"(v))

// LDS-only barrier: drain LDS ops, arrive, fence compiler. vmcnt stays live.
#define BAR() do { \
    asm volatile("s_waitcnt lgkmcnt(0)" ::: "memory"); \
    __builtin_amdgcn_s_barrier(); \
    asm volatile("" ::: "memory"); \
} while (0)

// pre is already scaled by 2*log2(e): tanh = 1 - 2/(2^pre + 1)
__device__ __forceinline__ float tanh_scaled(float pre) {
    float e = __builtin_amdgcn_exp2f(pre);
    float r = __builtin_amdgcn_rcpf(e + 1.0f);
    return __builtin_fmaf(-2.0f, r, 1.0f);
}
__device__ __forceinline__ v2f tanh2(v2f a) {
    v2f r; r.x = tanh_scaled(a.x); r.y = tanh_scaled(a.y); return r;
}
__device__ __forceinline__ v2f fma2(v2f a, v2f b, v2f c) {
    return __builtin_elementwise_fma(a, b, c);
}

__global__ void __launch_bounds__(128, 2)
rnn_fused(const int* __restrict__ x,
          const float* __restrict__ emb,
          const float* __restrict__ Wih0,
          const float* __restrict__ Whh0,
          const float* __restrict__ bih0,
          const float* __restrict__ bhh0,
          const float* __restrict__ Wih1,
          const float* __restrict__ Whh1,
          const float* __restrict__ bih1,
          const float* __restrict__ bhh1,
          const float* __restrict__ Wfc,
          const float* __restrict__ bfc,
          float* __restrict__ out)
{
    __shared__ __align__(16) float P[4][8];        // k-scaled L0 pre-activation table
    __shared__ __align__(16) v2f RING[2][6][64];   // [slot][plane][chain]: 0-3 h0 pairs, 4-5 z_lo

    const int tix = threadIdx.x;
    const int lane = tix & 63;

    if (tix < 32) {
        const int v = tix >> 3, l = tix & 7;
        float s = bih0[l] + bhh0[l];
        #pragma unroll
        for (int d = 0; d < EMB_D; ++d) s += Wih0[l * EMB_D + d] * emb[v * EMB_D + d];
        P[v][l] = s * KSCALE;
    }

    const int cid = blockIdx.x * 64 + lane;   // chain id; both waves: lane <-> chain
    const int b = cid & (B_LEN - 1);
    const int chunk = cid >> 11;              // uniform per block (64 | 2048)
    const int t_begin = chunk * CHUNK;
    const int t_end = t_begin + CHUNK;
    int t_start = t_begin - WARM;
    if (t_start < 0) t_start = 0;             // chunk 0: exact initial state
    const int NSTEPS = t_end - t_start;
    const int tmax = t_end - 1;

    __syncthreads();   // P ready

    if (tix < 64) {
        // ================= producer wave: L0 + low half of Wih1 =================
        v2f whh0pk[32], wih1lo[16], b1lo[2];
        #pragma unroll
        for (int p = 0; p < 4; ++p)
            #pragma unroll
            for (int j = 0; j < 8; ++j) {
                v2f w;
                w.x = Whh0[(2 * p) * 8 + j] * KSCALE;
                w.y = Whh0[(2 * p + 1) * 8 + j] * KSCALE;
                PINV(w); whh0pk[p * 8 + j] = w;
            }
        #pragma unroll
        for (int q = 0; q < 2; ++q)
            #pragma unroll
            for (int j = 0; j < 8; ++j) {
                v2f w;
                w.x = Wih1[(2 * q) * 8 + j] * KSCALE;
                w.y = Wih1[(2 * q + 1) * 8 + j] * KSCALE;
                PINV(w); wih1lo[q * 8 + j] = w;
            }
        #pragma unroll
        for (int q = 0; q < 2; ++q) {
            v2f w;
            w.x = (bih1[2 * q]     + bhh1[2 * q])     * KSCALE;
            w.y = (bih1[2 * q + 1] + bhh1[2 * q + 1]) * KSCALE;
            PINV(w); b1lo[q] = w;
        }

        const v2f* __restrict__ Ppk = (const v2f*)&P[0][0];
        v2f h0p[4];
        #pragma unroll
        for (int p = 0; p < 4; ++p) h0p[p] = (v2f){0.f, 0.f};

        int x0v = x[t_start * B_LEN + b];
        v2f pq[4];
        #pragma unroll
        for (int p = 0; p < 4; ++p) pq[p] = Ppk[x0v * 4 + p];
        int x1 = x[(t_start + 1) * B_LEN + b];

        for (int k = 0; k < NSTEPS; ++k) {
            BAR();
            const int t = t_start + k;
            int tp = t + 2; if (tp > tmax) tp = tmax;
            int x2 = x[tp * B_LEN + b];        // distance-2 x prefetch (vmcnt spans barriers)
            v2f nq[4];
            #pragma unroll
            for (int p = 0; p < 4; ++p) nq[p] = Ppk[x1 * 4 + p];

            // h0(t) = tanh(P[x_t] + Whh0 @ h0(t-1)), 4+4 tree
            v2f m[4], n[4];
            #pragma unroll
            for (int p = 0; p < 4; ++p) {
                m[p] = fma2(whh0pk[p * 8 + 0], h0p[0].xx, pq[p]);
                m[p] = fma2(whh0pk[p * 8 + 1], h0p[0].yy, m[p]);
                m[p] = fma2(whh0pk[p * 8 + 2], h0p[1].xx, m[p]);
                m[p] = fma2(whh0pk[p * 8 + 3], h0p[1].yy, m[p]);
                n[p] = whh0pk[p * 8 + 4] * h0p[2].xx;
                n[p] = fma2(whh0pk[p * 8 + 5], h0p[2].yy, n[p]);
                n[p] = fma2(whh0pk[p * 8 + 6], h0p[3].xx, n[p]);
                n[p] = fma2(whh0pk[p * 8 + 7], h0p[3].yy, n[p]);
            }
            #pragma unroll
            for (int p = 0; p < 4; ++p) h0p[p] = tanh2(m[p] + n[p]);

            // z_lo = b1[0:4] + Wih1[0:4,:] @ h0(t), 4+4 tree
            v2f zm[2], zn[2];
            #pragma unroll
            for (int q = 0; q < 2; ++q) {
                zm[q] = fma2(wih1lo[q * 8 + 0], h0p[0].xx, b1lo[q]);
                zm[q] = fma2(wih1lo[q * 8 + 1], h0p[0].yy, zm[q]);
                zm[q] = fma2(wih1lo[q * 8 + 2], h0p[1].xx, zm[q]);
                zm[q] = fma2(wih1lo[q * 8 + 3], h0p[1].yy, zm[q]);
                zn[q] = wih1lo[q * 8 + 4] * h0p[2].xx;
                zn[q] = fma2(wih1lo[q * 8 + 5], h0p[2].yy, zn[q]);
                zn[q] = fma2(wih1lo[q * 8 + 6], h0p[3].xx, zn[q]);
                zn[q] = fma2(wih1lo[q * 8 + 7], h0p[3].yy, zn[q]);
            }

            const int s = k & 1;
            #pragma unroll
            for (int p = 0; p < 4; ++p) RING[s][p][lane] = h0p[p];
            #pragma unroll
            for (int q = 0; q < 2; ++q) RING[s][4 + q][lane] = zm[q] + zn[q];

            #pragma unroll
            for (int p = 0; p < 4; ++p) pq[p] = nq[p];
            x1 = x2;
        }
        BAR();   // pairs with consumer's final iteration
    } else {
        // ============ consumer wave: high half Wih1 + Whh1 + tanh + FC ============
        v2f wih1hi[16], whh1pk[32], b1hi[2];
        #pragma unroll
        for (int q = 0; q < 2; ++q)
            #pragma unroll
            for (int j = 0; j < 8; ++j) {
                v2f w;
                w.x = Wih1[(4 + 2 * q) * 8 + j] * KSCALE;
                w.y = Wih1[(5 + 2 * q) * 8 + j] * KSCALE;
                PINV(w); wih1hi[q * 8 + j] = w;
            }
        #pragma unroll
        for (int p = 0; p < 4; ++p)
            #pragma unroll
            for (int j = 0; j < 8; ++j) {
                v2f w;
                w.x = Whh1[(2 * p) * 8 + j] * KSCALE;
                w.y = Whh1[(2 * p + 1) * 8 + j] * KSCALE;
                PINV(w); whh1pk[p * 8 + j] = w;
            }
        #pragma unroll
        for (int q = 0; q < 2; ++q) {
            v2f w;
            w.x = (bih1[4 + 2 * q] + bhh1[4 + 2 * q]) * KSCALE;
            w.y = (bih1[5 + 2 * q] + bhh1[5 + 2 * q]) * KSCALE;
            PINV(w); b1hi[q] = w;
        }
        float wfc[32], bf[4];
        #pragma unroll
        for (int i = 0; i < 32; ++i) { wfc[i] = Wfc[i]; PINS(wfc[i]); }
        #pragma unroll
        for (int i = 0; i < 4; ++i)  { bf[i] = bfc[i]; PINS(bf[i]); }

        v2f h1p[4];
        #pragma unroll
        for (int p = 0; p < 4; ++p) h1p[p] = (v2f){0.f, 0.f};
        float4* __restrict__ outv = (float4*)out;

        BAR();   // pairs with producer's k=0 barrier (nothing to consume yet)
        for (int k = 1; k <= NSTEPS; ++k) {
            BAR();
            const int u = t_start + k - 1;
            const int s = (k - 1) & 1;

            // issue ring reads first; Whh1 trees below hide the LDS latency
            v2f g[4], zl[2];
            #pragma unroll
            for (int p = 0; p < 4; ++p) g[p] = RING[s][p][lane];
            #pragma unroll
            for (int q = 0; q < 2; ++q) zl[q] = RING[s][4 + q][lane];

            // Whh1 @ h1(u-1): register-only, independent of ring data
            v2f m[4], n[4];
            #pragma unroll
            for (int p = 0; p < 4; ++p) {
                m[p] = whh1pk[p * 8 + 0] * h1p[0].xx;
                m[p] = fma2(whh1pk[p * 8 + 1], h1p[0].yy, m[p]);
                m[p] = fma2(whh1pk[p * 8 + 2], h1p[1].xx, m[p]);
                m[p] = fma2(whh1pk[p * 8 + 3], h1p[1].yy, m[p]);
                n[p] = whh1pk[p * 8 + 4] * h1p[2].xx;
                n[p] = fma2(whh1pk[p * 8 + 5], h1p[2].yy, n[p]);
                n[p] = fma2(whh1pk[p * 8 + 6], h1p[3].xx, n[p]);
                n[p] = fma2(whh1pk[p * 8 + 7], h1p[3].yy, n[p]);
            }

            // z_hi = b1[4:8] + Wih1[4:8,:] @ h0(u)
            v2f zm[2], zn[2];
            #pragma unroll
            for (int q = 0; q < 2; ++q) {
                zm[q] = fma2(wih1hi[q * 8 + 0], g[0].xx, b1hi[q]);
                zm[q] = fma2(wih1hi[q * 8 + 1], g[0].yy, zm[q]);
                zm[q] = fma2(wih1hi[q * 8 + 2], g[1].xx, zm[q]);
                zm[q] = fma2(wih1hi[q * 8 + 3], g[1].yy, zm[q]);
                zn[q] = wih1hi[q * 8 + 4] * g[2].xx;
                zn[q] = fma2(wih1hi[q * 8 + 5], g[2].yy, zn[q]);
                zn[q] = fma2(wih1hi[q * 8 + 6], g[3].xx, zn[q]);
                zn[q] = fma2(wih1hi[q * 8 + 7], g[3].yy, zn[q]);
            }

            v2f a1[4];
            a1[0] = zl[0] + (m[0] + n[0]);
            a1[1] = zl[1] + (m[1] + n[1]);
            a1[2] = (zm[0] + zn[0]) + (m[2] + n[2]);
            a1[3] = (zm[1] + zn[1]) + (m[3] + n[3]);
            #pragma unroll
            for (int p = 0; p < 4; ++p) h1p[p] = tanh2(a1[p]);

            if (u >= t_begin) {
                float s0 = bf[0], s1 = bf[1], s2 = bf[2], s3 = bf[3];
                #pragma unroll
                for (int q = 0; q < 4; ++q) {
                    s0 = __builtin_fmaf(wfc[0 * 8 + 2 * q], h1p[q].x, s0);
                    s0 = __builtin_fmaf(wfc[0 * 8 + 2 * q + 1], h1p[q].y, s0);
                    s1 = __builtin_fmaf(wfc[1 * 8 + 2 * q], h1p[q].x, s1);
                    s1 = __builtin_fmaf(wfc[1 * 8 + 2 * q + 1], h1p[q].y, s1);
                    s2 = __builtin_fmaf(wfc[2 * 8 + 2 * q], h1p[q].x, s2);
                    s2 = __builtin_fmaf(wfc[2 * 8 + 2 * q + 1], h1p[q].y, s2);
                    s3 = __builtin_fmaf(wfc[3 * 8 + 2 * q], h1p[q].x, s3);
                    s3 = __builtin_fmaf(wfc[3 * 8 + 2 * q + 1], h1p[q].y, s3);
                }
                float4 o; o.x = s0; o.y = s1; o.z = s2; o.w = s3;
                outv[u * B_LEN + b] = o;   // 16B/lane, coalesced; vmcnt spans barriers
            }
        }
    }
}

extern "C" void kernel_launch(void* const* d_in, const int* in_sizes, int n_in,
                              void* d_out, int out_size, void* d_ws, size_t ws_size,
                              hipStream_t stream) {
    const int*   x    = (const int*)d_in[0];
    const float* emb  = (const float*)d_in[1];
    const float* Wih0 = (const float*)d_in[2];
    const float* Whh0 = (const float*)d_in[3];
    const float* bih0 = (const float*)d_in[4];
    const float* bhh0 = (const float*)d_in[5];
    const float* Wih1 = (const float*)d_in[6];
    const float* Whh1 = (const float*)d_in[7];
    const float* bih1 = (const float*)d_in[8];
    const float* bhh1 = (const float*)d_in[9];
    const float* Wfc  = (const float*)d_in[10];
    const float* bfc  = (const float*)d_in[11];
    float* out = (float*)d_out;

    // 65536 chains, 64 per block; 128-thread blocks (producer + consumer wave).
    // 1024 blocks x 2 waves = 2048 waves = 2 waves/SIMD machine-wide.
    dim3 grid((B_LEN / 64) * NCHUNK);
    dim3 block(128);
    hipLaunchKernelGGL(rnn_fused, grid, block, 0, stream,
                       x, emb, Wih0, Whh0, bih0, bhh0,
                       Wih1, Whh1, bih1, bhh1, Wfc, bfc, out);
}